// Round 1
// baseline (318.207 us; speedup 1.0000x reference)
//
#include <hip/hip_runtime.h>
#include <hip/hip_bf16.h>

typedef unsigned short u16;
typedef unsigned int   u32;
typedef u16   u16x8 __attribute__((ext_vector_type(8)));
typedef u16   u16x4 __attribute__((ext_vector_type(4)));
typedef __bf16 bf16x8 __attribute__((ext_vector_type(8)));
typedef float f32x4 __attribute__((ext_vector_type(4)));

__device__ __forceinline__ u16 f2bf(float f) {
    u32 u = __float_as_uint(f);
    u = u + 0x7FFFu + ((u >> 16) & 1u);   // RTNE (inputs are finite)
    return (u16)(u >> 16);
}

// ---------------------------------------------------------------- converts --
__global__ __launch_bounds__(256) void cvt_x(const float* __restrict__ X,
                                             u16* __restrict__ Xb) {
    const long i = (long)(blockIdx.x * 256 + threadIdx.x) * 8;
    float4 a = *(const float4*)(X + i);
    float4 b = *(const float4*)(X + i + 4);
    u16x8 r;
    r[0] = f2bf(a.x); r[1] = f2bf(a.y); r[2] = f2bf(a.z); r[3] = f2bf(a.w);
    r[4] = f2bf(b.x); r[5] = f2bf(b.y); r[6] = f2bf(b.z); r[7] = f2bf(b.w);
    *(u16x8*)(Xb + i) = r;
}

// W [1024,1024] f32 -> WT bf16 [1024,1024], WT[n][k] = W[k][n]; 5 weights.
__global__ __launch_bounds__(256) void cvt_wT(const float* __restrict__ w0,
                                              const float* __restrict__ w1,
                                              const float* __restrict__ w2,
                                              const float* __restrict__ w3,
                                              const float* __restrict__ w4,
                                              u16* __restrict__ wt) {
    const float* srcs[5] = {w0, w1, w2, w3, w4};
    const float* W = srcs[blockIdx.z];
    u16* WT = wt + (long)blockIdx.z * 1048576;
    __shared__ float t[32][33];
    const int tx = threadIdx.x, ty = threadIdx.y;
    const int n0 = blockIdx.x * 32, k0 = blockIdx.y * 32;
    #pragma unroll
    for (int r = 0; r < 4; ++r)
        t[ty + 8 * r][tx] = W[(long)(k0 + ty + 8 * r) * 1024 + n0 + tx];
    __syncthreads();
    #pragma unroll
    for (int r = 0; r < 4; ++r)
        WT[(long)(n0 + ty + 8 * r) * 1024 + k0 + tx] = f2bf(t[tx][ty + 8 * r]);
}

// ------------------------------------------------------------------- GEMM ---
// C[M,N] = A[M,K] @ B^T  where Bt is stored [N,K] row-major (bf16 both).
// 256 thr, 4 waves 2x2, tile 128x128, BK=32, mfma_f32_16x16x32_bf16 4x4/wave.
#define BM 128
#define BN 128
#define BK 32
#define LDSK 40   // padded K-stride (80B -> 20-bank row stride, conflict-lite)

enum { EPI_BF16 = 0, EPI_VT = 1, EPI_SCALE_F32 = 2, EPI_ADDX_BF16 = 3,
       EPI_BIAS_RELU_BF16 = 4, EPI_BIAS_ADDX_F32 = 5 };

template <int EPI>
__global__ __launch_bounds__(256, 2)
void gemm_bt(const u16* __restrict__ A, const u16* __restrict__ Bt,
             void* __restrict__ Cout, const float* __restrict__ bias,
             const float* __restrict__ Xres,
             const int M, const int N, const int K,
             const long sA, const long sB, const long sC, const long sX,
             const float scale) {
    const int bz = blockIdx.z;
    const u16* Ab = A + (long)bz * sA;
    const u16* Bb = Bt + (long)bz * sB;
    const float* Xr = Xres ? Xres + (long)bz * sX : nullptr;

    const int tid  = threadIdx.x;
    const int lane = tid & 63;
    const int w    = tid >> 6;
    const int wr   = (w >> 1) * 64;
    const int wc   = (w & 1) * 64;
    const int m0   = blockIdx.x * BM;
    const int n0   = blockIdx.y * BN;

    __shared__ __align__(16) u16 As[BM * LDSK];
    __shared__ __align__(16) u16 Bs[BN * LDSK];

    f32x4 acc[4][4] = {};

    const int sr = tid >> 1;          // staging row (0..127)
    const int sc = (tid & 1) * 16;    // staging col base (0 or 16)
    const u16* Aptr = Ab + (long)(m0 + sr) * K + sc;
    const u16* Bptr = Bb + (long)(n0 + sr) * K + sc;

    const int rbase = lane & 15;
    const int koff  = (lane >> 4) * 8;

    for (int kt = 0; kt < K; kt += BK) {
        u16x8 a0 = *(const u16x8*)(Aptr + kt);
        u16x8 a1 = *(const u16x8*)(Aptr + kt + 8);
        u16x8 b0 = *(const u16x8*)(Bptr + kt);
        u16x8 b1 = *(const u16x8*)(Bptr + kt + 8);
        __syncthreads();
        *(u16x8*)(&As[sr * LDSK + sc])     = a0;
        *(u16x8*)(&As[sr * LDSK + sc + 8]) = a1;
        *(u16x8*)(&Bs[sr * LDSK + sc])     = b0;
        *(u16x8*)(&Bs[sr * LDSK + sc + 8]) = b1;
        __syncthreads();

        bf16x8 af[4], bfr[4];
        #pragma unroll
        for (int mi = 0; mi < 4; ++mi)
            af[mi] = *(const bf16x8*)(&As[(wr + mi * 16 + rbase) * LDSK + koff]);
        #pragma unroll
        for (int ni = 0; ni < 4; ++ni)
            bfr[ni] = *(const bf16x8*)(&Bs[(wc + ni * 16 + rbase) * LDSK + koff]);
        #pragma unroll
        for (int mi = 0; mi < 4; ++mi)
            #pragma unroll
            for (int ni = 0; ni < 4; ++ni)
                acc[mi][ni] = __builtin_amdgcn_mfma_f32_16x16x32_bf16(
                    af[mi], bfr[ni], acc[mi][ni], 0, 0, 0);
    }

    // ----------------------------------------------------------- epilogue --
    const int colb = wc + (lane & 15);
    const int rq   = (lane >> 4) * 4;
    #pragma unroll
    for (int mi = 0; mi < 4; ++mi) {
        #pragma unroll
        for (int ni = 0; ni < 4; ++ni) {
            f32x4 v = acc[mi][ni];
            const int gr0 = m0 + wr + mi * 16 + rq;   // first of 4 rows
            const int gc  = n0 + colb + ni * 16;
            if constexpr (EPI == EPI_VT) {
                // write V^T: VT[b][d=gc][s], batch from row; 4 contiguous s
                u16x4 p;
                p[0] = f2bf(v[0]); p[1] = f2bf(v[1]);
                p[2] = f2bf(v[2]); p[3] = f2bf(v[3]);
                u16* C = (u16*)Cout;
                const long off = ((long)(gr0 >> 11)) * 2097152 +
                                 (long)gc * 2048 + (gr0 & 2047);
                *(u16x4*)(C + off) = p;
            } else {
                #pragma unroll
                for (int j = 0; j < 4; ++j) {
                    const long idx = (long)(gr0 + j) * N + gc;
                    float val = v[j];
                    if constexpr (EPI == EPI_BF16) {
                        ((u16*)Cout + (long)bz * sC)[idx] = f2bf(val);
                    } else if constexpr (EPI == EPI_SCALE_F32) {
                        ((float*)Cout + (long)bz * sC)[idx] = val * scale;
                    } else if constexpr (EPI == EPI_ADDX_BF16) {
                        val += Xr[idx];
                        ((u16*)Cout + (long)bz * sC)[idx] = f2bf(val);
                    } else if constexpr (EPI == EPI_BIAS_RELU_BF16) {
                        val = fmaxf(val + bias[gc], 0.0f);
                        ((u16*)Cout + (long)bz * sC)[idx] = f2bf(val);
                    } else if constexpr (EPI == EPI_BIAS_ADDX_F32) {
                        ((float*)Cout + (long)bz * sC)[idx] =
                            val + bias[gc] + Xr[idx];
                    }
                }
            }
        }
    }
}

// ---------------------------------------------------------------- softmax ---
// one block per row of attn (len 2048); fp32 in-place + bf16 copy for PV.
__global__ __launch_bounds__(256)
void softmax_rows(float* __restrict__ attn, u16* __restrict__ P) {
    const int row  = blockIdx.x;
    float* rp      = attn + (long)row * 2048;
    const int tid  = threadIdx.x;
    const int lane = tid & 63;
    const int w    = tid >> 6;

    float4 v0 = *(const float4*)(rp + tid * 8);
    float4 v1 = *(const float4*)(rp + tid * 8 + 4);

    float m = fmaxf(fmaxf(fmaxf(v0.x, v0.y), fmaxf(v0.z, v0.w)),
                    fmaxf(fmaxf(v1.x, v1.y), fmaxf(v1.z, v1.w)));
    #pragma unroll
    for (int o = 32; o > 0; o >>= 1) m = fmaxf(m, __shfl_xor(m, o));
    __shared__ float redm[4];
    if (lane == 0) redm[w] = m;
    __syncthreads();
    m = fmaxf(fmaxf(redm[0], redm[1]), fmaxf(redm[2], redm[3]));

    float e[8];
    e[0] = __expf(v0.x - m); e[1] = __expf(v0.y - m);
    e[2] = __expf(v0.z - m); e[3] = __expf(v0.w - m);
    e[4] = __expf(v1.x - m); e[5] = __expf(v1.y - m);
    e[6] = __expf(v1.z - m); e[7] = __expf(v1.w - m);
    float s = ((e[0] + e[1]) + (e[2] + e[3])) + ((e[4] + e[5]) + (e[6] + e[7]));
    #pragma unroll
    for (int o = 32; o > 0; o >>= 1) s += __shfl_xor(s, o);
    __shared__ float reds[4];
    if (lane == 0) reds[w] = s;
    __syncthreads();
    s = (reds[0] + reds[1]) + (reds[2] + reds[3]);
    const float inv = 1.0f / s;

    float4 o0, o1;
    o0.x = e[0] * inv; o0.y = e[1] * inv; o0.z = e[2] * inv; o0.w = e[3] * inv;
    o1.x = e[4] * inv; o1.y = e[5] * inv; o1.z = e[6] * inv; o1.w = e[7] * inv;
    *(float4*)(rp + tid * 8)     = o0;
    *(float4*)(rp + tid * 8 + 4) = o1;

    u16x8 pb;
    pb[0] = f2bf(o0.x); pb[1] = f2bf(o0.y); pb[2] = f2bf(o0.z); pb[3] = f2bf(o0.w);
    pb[4] = f2bf(o1.x); pb[5] = f2bf(o1.y); pb[6] = f2bf(o1.z); pb[7] = f2bf(o1.w);
    *(u16x8*)(P + (long)row * 2048 + tid * 8) = pb;
}

// ------------------------------------------------------------------ launch --
extern "C" void kernel_launch(void* const* d_in, const int* in_sizes, int n_in,
                              void* d_out, int out_size, void* d_ws, size_t ws_size,
                              hipStream_t stream) {
    const float* X  = (const float*)d_in[0];
    const float* Wq = (const float*)d_in[1];
    const float* Wk = (const float*)d_in[2];
    const float* Wv = (const float*)d_in[3];
    const float* W1 = (const float*)d_in[4];
    const float* b1 = (const float*)d_in[5];
    const float* W2 = (const float*)d_in[6];
    const float* b2 = (const float*)d_in[7];

    float* out  = (float*)d_out;                    // [4,2048,1024]
    float* attn = out + (size_t)8388608;            // [4,2048,2048]

    char* ws = (char*)d_ws;
    u16* Xb  = (u16*)(ws);                               // 16 MiB
    u16* Qb  = (u16*)(ws + (size_t)16 * 1024 * 1024);    // 16 MiB
    u16* Kb  = (u16*)(ws + (size_t)32 * 1024 * 1024);    // 16 MiB
    u16* VT  = (u16*)(ws + (size_t)48 * 1024 * 1024);    // 16 MiB  V^T [b][d][s]
    u16* H1b = (u16*)(ws + (size_t)64 * 1024 * 1024);    // 16 MiB
    u16* WTs = (u16*)(ws + (size_t)80 * 1024 * 1024);    // 10 MiB (5 x 2 MiB)
    u16* WqT = WTs + (size_t)0 * 1048576;
    u16* WkT = WTs + (size_t)1 * 1048576;
    u16* WvT = WTs + (size_t)2 * 1048576;
    u16* W1T = WTs + (size_t)3 * 1048576;
    u16* W2T = WTs + (size_t)4 * 1048576;
    u16* Pb  = Xb;   // 32 MiB alias over Xb+Qb (both dead by softmax time)
    u16* Hb  = Kb;   // alias over Kb (dead after scores GEMM)

    cvt_x<<<4096, 256, 0, stream>>>(X, Xb);
    cvt_wT<<<dim3(32, 32, 5), dim3(32, 8), 0, stream>>>(Wq, Wk, Wv, W1, W2, WTs);

    // Q, K, V(=V^T direct)
    gemm_bt<EPI_BF16><<<dim3(64, 8, 1), 256, 0, stream>>>(
        Xb, WqT, Qb, nullptr, nullptr, 8192, 1024, 1024, 0, 0, 0, 0, 1.0f);
    gemm_bt<EPI_BF16><<<dim3(64, 8, 1), 256, 0, stream>>>(
        Xb, WkT, Kb, nullptr, nullptr, 8192, 1024, 1024, 0, 0, 0, 0, 1.0f);
    gemm_bt<EPI_VT><<<dim3(64, 8, 1), 256, 0, stream>>>(
        Xb, WvT, VT, nullptr, nullptr, 8192, 1024, 1024, 0, 0, 0, 0, 1.0f);

    // scores = Q @ K^T / 32  -> fp32 raw into d_out attn region
    gemm_bt<EPI_SCALE_F32><<<dim3(16, 16, 4), 256, 0, stream>>>(
        Qb, Kb, attn, nullptr, nullptr, 2048, 2048, 1024,
        2048L * 1024, 2048L * 1024, 2048L * 2048, 0, 0.03125f);

    softmax_rows<<<8192, 256, 0, stream>>>(attn, Pb);

    // attn_out = P @ V, + X residual -> Hb (bf16)
    gemm_bt<EPI_ADDX_BF16><<<dim3(16, 8, 4), 256, 0, stream>>>(
        Pb, VT, Hb, nullptr, X, 2048, 1024, 2048,
        2048L * 2048, 1024L * 2048, 2048L * 1024, 2048L * 1024, 1.0f);

    // h1 = relu(Hb @ W1 + b1)
    gemm_bt<EPI_BIAS_RELU_BF16><<<dim3(64, 8, 1), 256, 0, stream>>>(
        Hb, W1T, H1b, b1, nullptr, 8192, 1024, 1024, 0, 0, 0, 0, 1.0f);

    // out = h1 @ W2 + b2 + X
    gemm_bt<EPI_BIAS_ADDX_F32><<<dim3(64, 8, 1), 256, 0, stream>>>(
        H1b, W2T, out, b2, X, 8192, 1024, 1024, 0, 0, 0, 0, 1.0f);
}

// Round 2
// 283.092 us; speedup vs baseline: 1.1240x; 1.1240x over previous
//
#include <hip/hip_runtime.h>
#include <hip/hip_bf16.h>

typedef unsigned short u16;
typedef unsigned int   u32;
typedef u16   u16x8 __attribute__((ext_vector_type(8)));
typedef u16   u16x4 __attribute__((ext_vector_type(4)));
typedef __bf16 bf16x8 __attribute__((ext_vector_type(8)));
typedef float f32x4 __attribute__((ext_vector_type(4)));

__device__ __forceinline__ u16 f2bf(float f) {
    u32 u = __float_as_uint(f);
    u = u + 0x7FFFu + ((u >> 16) & 1u);   // RTNE (inputs are finite)
    return (u16)(u >> 16);
}

// async global->LDS, 16B per lane; LDS dest is wave-uniform base + lane*16
__device__ __forceinline__ void gload16(const u16* g, u16* l) {
    __builtin_amdgcn_global_load_lds(
        (const __attribute__((address_space(1))) void*)g,
        (__attribute__((address_space(3))) void*)l,
        16, 0, 0);
}

// ---------------------------------------------------------------- converts --
__global__ __launch_bounds__(256) void cvt_x(const float* __restrict__ X,
                                             u16* __restrict__ Xb) {
    const long i = (long)(blockIdx.x * 256 + threadIdx.x) * 8;
    float4 a = *(const float4*)(X + i);
    float4 b = *(const float4*)(X + i + 4);
    u16x8 r;
    r[0] = f2bf(a.x); r[1] = f2bf(a.y); r[2] = f2bf(a.z); r[3] = f2bf(a.w);
    r[4] = f2bf(b.x); r[5] = f2bf(b.y); r[6] = f2bf(b.z); r[7] = f2bf(b.w);
    *(u16x8*)(Xb + i) = r;
}

// W [1024,1024] f32 -> WT bf16 [1024,1024], WT[n][k] = W[k][n]; 5 weights.
__global__ __launch_bounds__(256) void cvt_wT(const float* __restrict__ w0,
                                              const float* __restrict__ w1,
                                              const float* __restrict__ w2,
                                              const float* __restrict__ w3,
                                              const float* __restrict__ w4,
                                              u16* __restrict__ wt) {
    const float* srcs[5] = {w0, w1, w2, w3, w4};
    const float* W = srcs[blockIdx.z];
    u16* WT = wt + (long)blockIdx.z * 1048576;
    __shared__ float t[32][33];
    const int tx = threadIdx.x, ty = threadIdx.y;
    const int n0 = blockIdx.x * 32, k0 = blockIdx.y * 32;
    #pragma unroll
    for (int r = 0; r < 4; ++r)
        t[ty + 8 * r][tx] = W[(long)(k0 + ty + 8 * r) * 1024 + n0 + tx];
    __syncthreads();
    #pragma unroll
    for (int r = 0; r < 4; ++r)
        WT[(long)(n0 + ty + 8 * r) * 1024 + k0 + tx] = f2bf(t[tx][ty + 8 * r]);
}

// ------------------------------------------------------------------- GEMM ---
// C[M,N] = A[M,K] @ B^T  where Bt is stored [N,K] row-major (bf16 both).
// 256 thr, 4 waves 2x2, tile 128x128, BK=32, mfma_f32_16x16x32_bf16 4x4/wave.
// m97 structure: global_load_lds width-16 staging, linear LDS [128][32]
// (64B rows = 16-bank stride; the 4 koff-groups of the b128 fragment read
// tile all 32 banks at the 8-access minimum -> conflict-free, no pad needed).
#define BM 128
#define BN 128
#define BK 32

enum { EPI_BF16 = 0, EPI_VT = 1, EPI_SCALE_F32 = 2, EPI_ADDX_BF16 = 3,
       EPI_BIAS_RELU_BF16 = 4, EPI_BIAS_ADDX_F32 = 5 };

template <int EPI>
__global__ __launch_bounds__(256, 2)
void gemm_bt(const u16* __restrict__ A, const u16* __restrict__ Bt,
             void* __restrict__ Cout, const float* __restrict__ bias,
             const float* __restrict__ Xres,
             const int M, const int N, const int K,
             const long sA, const long sB, const long sC, const long sX,
             const float scale) {
    const int bz = blockIdx.z;
    const u16* Ab = A + (long)bz * sA;
    const u16* Bb = Bt + (long)bz * sB;
    const float* Xr = Xres ? Xres + (long)bz * sX : nullptr;

    const int tid  = threadIdx.x;
    const int lane = tid & 63;
    const int w    = tid >> 6;
    const int wr   = (w >> 1) * 64;
    const int wc   = (w & 1) * 64;
    const int m0   = blockIdx.x * BM;
    const int n0   = blockIdx.y * BN;

    __shared__ __align__(16) u16 As[BM * BK];   // 8 KiB
    __shared__ __align__(16) u16 Bs[BN * BK];   // 8 KiB

    f32x4 acc[4][4] = {};

    // staging: wave w owns rows [w*32, w*32+32) of each tile; 2 gload16 per
    // operand (16 rows x 64B each). lane l -> row l>>2, col-elem (l&3)*8.
    const u16* Ag = Ab + (long)(m0 + w * 32 + (lane >> 2)) * K + (lane & 3) * 8;
    const u16* Bg = Bb + (long)(n0 + w * 32 + (lane >> 2)) * K + (lane & 3) * 8;
    const long r16A = 16L * K;
    u16* As0 = &As[(w * 32) * BK];
    u16* As1 = &As[(w * 32 + 16) * BK];
    u16* Bs0 = &Bs[(w * 32) * BK];
    u16* Bs1 = &Bs[(w * 32 + 16) * BK];

    const int rbase = lane & 15;
    const int koff  = (lane >> 4) * 8;

    for (int kt = 0; kt < K; kt += BK) {
        gload16(Ag + kt, As0);
        gload16(Ag + kt + r16A, As1);
        gload16(Bg + kt, Bs0);
        gload16(Bg + kt + r16A, Bs1);
        __syncthreads();   // drains vmcnt -> tile resident

        bf16x8 af[4], bfr[4];
        #pragma unroll
        for (int mi = 0; mi < 4; ++mi)
            af[mi] = *(const bf16x8*)(&As[(wr + mi * 16 + rbase) * BK + koff]);
        #pragma unroll
        for (int ni = 0; ni < 4; ++ni)
            bfr[ni] = *(const bf16x8*)(&Bs[(wc + ni * 16 + rbase) * BK + koff]);
        #pragma unroll
        for (int mi = 0; mi < 4; ++mi)
            #pragma unroll
            for (int ni = 0; ni < 4; ++ni)
                acc[mi][ni] = __builtin_amdgcn_mfma_f32_16x16x32_bf16(
                    af[mi], bfr[ni], acc[mi][ni], 0, 0, 0);
        __syncthreads();   // all readers done before next iter overwrites
    }

    // ----------------------------------------------------------- epilogue --
    const int colb = wc + (lane & 15);
    const int rq   = (lane >> 4) * 4;
    #pragma unroll
    for (int mi = 0; mi < 4; ++mi) {
        #pragma unroll
        for (int ni = 0; ni < 4; ++ni) {
            f32x4 v = acc[mi][ni];
            const int gr0 = m0 + wr + mi * 16 + rq;   // first of 4 rows
            const int gc  = n0 + colb + ni * 16;
            if constexpr (EPI == EPI_VT) {
                // write V^T: VT[b][d=gc][s], batch from row; 4 contiguous s
                u16x4 p;
                p[0] = f2bf(v[0]); p[1] = f2bf(v[1]);
                p[2] = f2bf(v[2]); p[3] = f2bf(v[3]);
                u16* C = (u16*)Cout;
                const long off = ((long)(gr0 >> 11)) * 2097152 +
                                 (long)gc * 2048 + (gr0 & 2047);
                *(u16x4*)(C + off) = p;
            } else {
                #pragma unroll
                for (int j = 0; j < 4; ++j) {
                    const long idx = (long)(gr0 + j) * N + gc;
                    float val = v[j];
                    if constexpr (EPI == EPI_BF16) {
                        ((u16*)Cout + (long)bz * sC)[idx] = f2bf(val);
                    } else if constexpr (EPI == EPI_SCALE_F32) {
                        ((float*)Cout + (long)bz * sC)[idx] = val * scale;
                    } else if constexpr (EPI == EPI_ADDX_BF16) {
                        val += Xr[idx];
                        ((u16*)Cout + (long)bz * sC)[idx] = f2bf(val);
                    } else if constexpr (EPI == EPI_BIAS_RELU_BF16) {
                        val = fmaxf(val + bias[gc], 0.0f);
                        ((u16*)Cout + (long)bz * sC)[idx] = f2bf(val);
                    } else if constexpr (EPI == EPI_BIAS_ADDX_F32) {
                        ((float*)Cout + (long)bz * sC)[idx] =
                            val + bias[gc] + Xr[idx];
                    }
                }
            }
        }
    }
}

// ---------------------------------------------------------------- softmax ---
// one block per row of attn (len 2048); fp32 in-place + bf16 copy for PV.
__global__ __launch_bounds__(256)
void softmax_rows(float* __restrict__ attn, u16* __restrict__ P) {
    const int row  = blockIdx.x;
    float* rp      = attn + (long)row * 2048;
    const int tid  = threadIdx.x;
    const int lane = tid & 63;
    const int w    = tid >> 6;

    float4 v0 = *(const float4*)(rp + tid * 8);
    float4 v1 = *(const float4*)(rp + tid * 8 + 4);

    float m = fmaxf(fmaxf(fmaxf(v0.x, v0.y), fmaxf(v0.z, v0.w)),
                    fmaxf(fmaxf(v1.x, v1.y), fmaxf(v1.z, v1.w)));
    #pragma unroll
    for (int o = 32; o > 0; o >>= 1) m = fmaxf(m, __shfl_xor(m, o));
    __shared__ float redm[4];
    if (lane == 0) redm[w] = m;
    __syncthreads();
    m = fmaxf(fmaxf(redm[0], redm[1]), fmaxf(redm[2], redm[3]));

    float e[8];
    e[0] = __expf(v0.x - m); e[1] = __expf(v0.y - m);
    e[2] = __expf(v0.z - m); e[3] = __expf(v0.w - m);
    e[4] = __expf(v1.x - m); e[5] = __expf(v1.y - m);
    e[6] = __expf(v1.z - m); e[7] = __expf(v1.w - m);
    float s = ((e[0] + e[1]) + (e[2] + e[3])) + ((e[4] + e[5]) + (e[6] + e[7]));
    #pragma unroll
    for (int o = 32; o > 0; o >>= 1) s += __shfl_xor(s, o);
    __shared__ float reds[4];
    if (lane == 0) reds[w] = s;
    __syncthreads();
    s = (reds[0] + reds[1]) + (reds[2] + reds[3]);
    const float inv = 1.0f / s;

    float4 o0, o1;
    o0.x = e[0] * inv; o0.y = e[1] * inv; o0.z = e[2] * inv; o0.w = e[3] * inv;
    o1.x = e[4] * inv; o1.y = e[5] * inv; o1.z = e[6] * inv; o1.w = e[7] * inv;
    *(float4*)(rp + tid * 8)     = o0;
    *(float4*)(rp + tid * 8 + 4) = o1;

    u16x8 pb;
    pb[0] = f2bf(o0.x); pb[1] = f2bf(o0.y); pb[2] = f2bf(o0.z); pb[3] = f2bf(o0.w);
    pb[4] = f2bf(o1.x); pb[5] = f2bf(o1.y); pb[6] = f2bf(o1.z); pb[7] = f2bf(o1.w);
    *(u16x8*)(P + (long)row * 2048 + tid * 8) = pb;
}

// ------------------------------------------------------------------ launch --
extern "C" void kernel_launch(void* const* d_in, const int* in_sizes, int n_in,
                              void* d_out, int out_size, void* d_ws, size_t ws_size,
                              hipStream_t stream) {
    const float* X  = (const float*)d_in[0];
    const float* Wq = (const float*)d_in[1];
    const float* Wk = (const float*)d_in[2];
    const float* Wv = (const float*)d_in[3];
    const float* W1 = (const float*)d_in[4];
    const float* b1 = (const float*)d_in[5];
    const float* W2 = (const float*)d_in[6];
    const float* b2 = (const float*)d_in[7];

    float* out  = (float*)d_out;                    // [4,2048,1024]
    float* attn = out + (size_t)8388608;            // [4,2048,2048]

    char* ws = (char*)d_ws;
    u16* Xb  = (u16*)(ws);                               // 16 MiB
    u16* Qb  = (u16*)(ws + (size_t)16 * 1024 * 1024);    // 16 MiB
    u16* Kb  = (u16*)(ws + (size_t)32 * 1024 * 1024);    // 16 MiB
    u16* VT  = (u16*)(ws + (size_t)48 * 1024 * 1024);    // 16 MiB  V^T [b][d][s]
    u16* H1b = (u16*)(ws + (size_t)64 * 1024 * 1024);    // 16 MiB
    u16* WTs = (u16*)(ws + (size_t)80 * 1024 * 1024);    // 10 MiB (5 x 2 MiB)
    u16* WqT = WTs + (size_t)0 * 1048576;
    u16* WkT = WTs + (size_t)1 * 1048576;
    u16* WvT = WTs + (size_t)2 * 1048576;
    u16* W1T = WTs + (size_t)3 * 1048576;
    u16* W2T = WTs + (size_t)4 * 1048576;
    u16* Pb  = Xb;   // 32 MiB alias over Xb+Qb (both dead by softmax time)
    u16* Hb  = Kb;   // alias over Kb (dead after scores GEMM)

    cvt_x<<<4096, 256, 0, stream>>>(X, Xb);
    cvt_wT<<<dim3(32, 32, 5), dim3(32, 8), 0, stream>>>(Wq, Wk, Wv, W1, W2, WTs);

    // Q, K, V(=V^T direct)
    gemm_bt<EPI_BF16><<<dim3(64, 8, 1), 256, 0, stream>>>(
        Xb, WqT, Qb, nullptr, nullptr, 8192, 1024, 1024, 0, 0, 0, 0, 1.0f);
    gemm_bt<EPI_BF16><<<dim3(64, 8, 1), 256, 0, stream>>>(
        Xb, WkT, Kb, nullptr, nullptr, 8192, 1024, 1024, 0, 0, 0, 0, 1.0f);
    gemm_bt<EPI_VT><<<dim3(64, 8, 1), 256, 0, stream>>>(
        Xb, WvT, VT, nullptr, nullptr, 8192, 1024, 1024, 0, 0, 0, 0, 1.0f);

    // scores = Q @ K^T / 32  -> fp32 raw into d_out attn region
    gemm_bt<EPI_SCALE_F32><<<dim3(16, 16, 4), 256, 0, stream>>>(
        Qb, Kb, attn, nullptr, nullptr, 2048, 2048, 1024,
        2048L * 1024, 2048L * 1024, 2048L * 2048, 0, 0.03125f);

    softmax_rows<<<8192, 256, 0, stream>>>(attn, Pb);

    // attn_out = P @ V, + X residual -> Hb (bf16)
    gemm_bt<EPI_ADDX_BF16><<<dim3(16, 8, 4), 256, 0, stream>>>(
        Pb, VT, Hb, nullptr, X, 2048, 1024, 2048,
        2048L * 2048, 1024L * 2048, 2048L * 1024, 2048L * 1024, 1.0f);

    // h1 = relu(Hb @ W1 + b1)
    gemm_bt<EPI_BIAS_RELU_BF16><<<dim3(64, 8, 1), 256, 0, stream>>>(
        Hb, W1T, H1b, b1, nullptr, 8192, 1024, 1024, 0, 0, 0, 0, 1.0f);

    // out = h1 @ W2 + b2 + X
    gemm_bt<EPI_BIAS_ADDX_F32><<<dim3(64, 8, 1), 256, 0, stream>>>(
        H1b, W2T, out, b2, X, 8192, 1024, 1024, 0, 0, 0, 0, 1.0f);
}

// Round 3
// 266.462 us; speedup vs baseline: 1.1942x; 1.0624x over previous
//
#include <hip/hip_runtime.h>
#include <hip/hip_bf16.h>

typedef unsigned short u16;
typedef unsigned int   u32;
typedef u16   u16x8 __attribute__((ext_vector_type(8)));
typedef u16   u16x4 __attribute__((ext_vector_type(4)));
typedef __bf16 bf16x8 __attribute__((ext_vector_type(8)));
typedef float f32x4 __attribute__((ext_vector_type(4)));

__device__ __forceinline__ u16 f2bf(float f) {
    u32 u = __float_as_uint(f);
    u = u + 0x7FFFu + ((u >> 16) & 1u);   // RTNE (inputs are finite)
    return (u16)(u >> 16);
}

// async global->LDS, 16B per lane; LDS dest is wave-uniform base + lane*16
__device__ __forceinline__ void gload16(const u16* g, u16* l) {
    __builtin_amdgcn_global_load_lds(
        (const __attribute__((address_space(1))) void*)g,
        (__attribute__((address_space(3))) void*)l,
        16, 0, 0);
}

// ---------------------------------------------------------------- converts --
__global__ __launch_bounds__(256) void cvt_x(const float* __restrict__ X,
                                             u16* __restrict__ Xb) {
    const long i = (long)(blockIdx.x * 256 + threadIdx.x) * 8;
    float4 a = *(const float4*)(X + i);
    float4 b = *(const float4*)(X + i + 4);
    u16x8 r;
    r[0] = f2bf(a.x); r[1] = f2bf(a.y); r[2] = f2bf(a.z); r[3] = f2bf(a.w);
    r[4] = f2bf(b.x); r[5] = f2bf(b.y); r[6] = f2bf(b.z); r[7] = f2bf(b.w);
    *(u16x8*)(Xb + i) = r;
}

// W [1024,1024] f32 -> WT bf16 [1024,1024], WT[n][k] = W[k][n]; 5 weights.
__global__ __launch_bounds__(256) void cvt_wT(const float* __restrict__ w0,
                                              const float* __restrict__ w1,
                                              const float* __restrict__ w2,
                                              const float* __restrict__ w3,
                                              const float* __restrict__ w4,
                                              u16* __restrict__ wt) {
    const float* srcs[5] = {w0, w1, w2, w3, w4};
    const float* W = srcs[blockIdx.z];
    u16* WT = wt + (long)blockIdx.z * 1048576;
    __shared__ float t[32][33];
    const int tx = threadIdx.x, ty = threadIdx.y;
    const int n0 = blockIdx.x * 32, k0 = blockIdx.y * 32;
    #pragma unroll
    for (int r = 0; r < 4; ++r)
        t[ty + 8 * r][tx] = W[(long)(k0 + ty + 8 * r) * 1024 + n0 + tx];
    __syncthreads();
    #pragma unroll
    for (int r = 0; r < 4; ++r)
        WT[(long)(n0 + ty + 8 * r) * 1024 + k0 + tx] = f2bf(t[tx][ty + 8 * r]);
}

// ------------------------------------------------------------------- GEMM ---
// C[M,N] = A[M,K] @ B^T  where Bt is stored [N,K] row-major (bf16 both).
// 256 thr, 4 waves 2x2, tile 128x128, BK=32, mfma_f32_16x16x32_bf16 4x4/wave.
// m97 structure + chunk swizzle: LDS[row][s] = G[row][s ^ ((row>>1)&3)]
// (pre-swizzled global source, linear LDS dest — rule #21). Fragment
// ds_read_b128 then hits each bank exactly 4x per half-wave (b128 minimum).
#define BM 128
#define BN 128
#define BK 32

enum { EPI_QKV = 0, EPI_SCALE_F32 = 2, EPI_ADDX_BF16 = 3,
       EPI_BIAS_RELU_BF16 = 4, EPI_BIAS_ADDX_F32 = 5 };

template <int EPI>
__global__ __launch_bounds__(256, 2)
void gemm_bt(const u16* __restrict__ A, const u16* __restrict__ Bt,
             void* __restrict__ Cout, void* __restrict__ CoutK,
             void* __restrict__ CoutV,
             const float* __restrict__ bias, const float* __restrict__ Xres,
             const int M, const int N, const int K,
             const long sA, const long sB, const long sC, const long sX,
             const float scale) {
    const int bz = blockIdx.z;
    const u16* Ab = A + (long)bz * sA;
    const u16* Bb = Bt + (long)bz * sB;
    const float* Xr = Xres ? Xres + (long)bz * sX : nullptr;

    const int tid  = threadIdx.x;
    const int lane = tid & 63;
    const int w    = tid >> 6;
    const int wr   = (w >> 1) * 64;
    const int wc   = (w & 1) * 64;
    const int m0   = blockIdx.x * BM;
    const int n0   = blockIdx.y * BN;

    __shared__ __align__(16) u16 As[BM * BK];   // 8 KiB
    __shared__ __align__(16) u16 Bs[BN * BK];   // 8 KiB

    f32x4 acc[4][4] = {};

    // staging: wave w owns rows [w*32, w*32+32); lane l -> row l>>2, LDS slot
    // l&3; source chunk = (l&3) ^ ((l>>3)&3)  (the row-swizzle term reduces
    // to (l>>3)&3 since w*32 and +16 contribute 0 mod 4 after >>1).
    const int schunk = ((lane & 3) ^ ((lane >> 3) & 3)) * 8;
    const u16* Ag = Ab + (long)(m0 + w * 32 + (lane >> 2)) * K + schunk;
    const u16* Bg = Bb + (long)(n0 + w * 32 + (lane >> 2)) * K + schunk;
    const long r16A = 16L * K;
    u16* As0 = &As[(w * 32) * BK];
    u16* As1 = &As[(w * 32 + 16) * BK];
    u16* Bs0 = &Bs[(w * 32) * BK];
    u16* Bs1 = &Bs[(w * 32 + 16) * BK];

    const int rbase = lane & 15;
    // read-side swizzle: chunk g = lane>>4 lives at slot g ^ ((rbase>>1)&3)
    const int koff  = (((lane >> 4) ^ ((rbase >> 1) & 3))) * 8;

    for (int kt = 0; kt < K; kt += BK) {
        gload16(Ag + kt, As0);
        gload16(Ag + kt + r16A, As1);
        gload16(Bg + kt, Bs0);
        gload16(Bg + kt + r16A, Bs1);
        __syncthreads();   // drains vmcnt -> tile resident

        bf16x8 af[4], bfr[4];
        #pragma unroll
        for (int mi = 0; mi < 4; ++mi)
            af[mi] = *(const bf16x8*)(&As[(wr + mi * 16 + rbase) * BK + koff]);
        #pragma unroll
        for (int ni = 0; ni < 4; ++ni)
            bfr[ni] = *(const bf16x8*)(&Bs[(wc + ni * 16 + rbase) * BK + koff]);
        #pragma unroll
        for (int mi = 0; mi < 4; ++mi)
            #pragma unroll
            for (int ni = 0; ni < 4; ++ni)
                acc[mi][ni] = __builtin_amdgcn_mfma_f32_16x16x32_bf16(
                    af[mi], bfr[ni], acc[mi][ni], 0, 0, 0);
        __syncthreads();   // all readers done before next iter overwrites
    }

    // ----------------------------------------------------------- epilogue --
    const int colb = wc + (lane & 15);
    const int rq   = (lane >> 4) * 4;
    #pragma unroll
    for (int mi = 0; mi < 4; ++mi) {
        #pragma unroll
        for (int ni = 0; ni < 4; ++ni) {
            f32x4 v = acc[mi][ni];
            const int gr0 = m0 + wr + mi * 16 + rq;   // first of 4 rows
            const int gc  = n0 + colb + ni * 16;
            if constexpr (EPI == EPI_QKV) {
                if (bz == 2) {
                    // V -> write V^T: VT[b][d=gc][s]; 4 contiguous s
                    u16x4 p;
                    p[0] = f2bf(v[0]); p[1] = f2bf(v[1]);
                    p[2] = f2bf(v[2]); p[3] = f2bf(v[3]);
                    u16* C = (u16*)CoutV;
                    const long off = ((long)(gr0 >> 11)) * 2097152 +
                                     (long)gc * 2048 + (gr0 & 2047);
                    *(u16x4*)(C + off) = p;
                } else {
                    u16* C = (u16*)(bz == 0 ? Cout : CoutK);
                    #pragma unroll
                    for (int j = 0; j < 4; ++j)
                        C[(long)(gr0 + j) * N + gc] = f2bf(v[j]);
                }
            } else {
                #pragma unroll
                for (int j = 0; j < 4; ++j) {
                    const long idx = (long)(gr0 + j) * N + gc;
                    float val = v[j];
                    if constexpr (EPI == EPI_SCALE_F32) {
                        ((float*)Cout + (long)bz * sC)[idx] = val * scale;
                    } else if constexpr (EPI == EPI_ADDX_BF16) {
                        val += Xr[idx];
                        ((u16*)Cout + (long)bz * sC)[idx] = f2bf(val);
                    } else if constexpr (EPI == EPI_BIAS_RELU_BF16) {
                        val = fmaxf(val + bias[gc], 0.0f);
                        ((u16*)Cout + (long)bz * sC)[idx] = f2bf(val);
                    } else if constexpr (EPI == EPI_BIAS_ADDX_F32) {
                        ((float*)Cout + (long)bz * sC)[idx] =
                            val + bias[gc] + Xr[idx];
                    }
                }
            }
        }
    }
}

// ---------------------------------------------------------------- softmax ---
// one block per row of attn (len 2048); fp32 in-place + bf16 copy for PV.
__global__ __launch_bounds__(256)
void softmax_rows(float* __restrict__ attn, u16* __restrict__ P) {
    const int row  = blockIdx.x;
    float* rp      = attn + (long)row * 2048;
    const int tid  = threadIdx.x;
    const int lane = tid & 63;
    const int w    = tid >> 6;

    float4 v0 = *(const float4*)(rp + tid * 8);
    float4 v1 = *(const float4*)(rp + tid * 8 + 4);

    float m = fmaxf(fmaxf(fmaxf(v0.x, v0.y), fmaxf(v0.z, v0.w)),
                    fmaxf(fmaxf(v1.x, v1.y), fmaxf(v1.z, v1.w)));
    #pragma unroll
    for (int o = 32; o > 0; o >>= 1) m = fmaxf(m, __shfl_xor(m, o));
    __shared__ float redm[4];
    if (lane == 0) redm[w] = m;
    __syncthreads();
    m = fmaxf(fmaxf(redm[0], redm[1]), fmaxf(redm[2], redm[3]));

    float e[8];
    e[0] = __expf(v0.x - m); e[1] = __expf(v0.y - m);
    e[2] = __expf(v0.z - m); e[3] = __expf(v0.w - m);
    e[4] = __expf(v1.x - m); e[5] = __expf(v1.y - m);
    e[6] = __expf(v1.z - m); e[7] = __expf(v1.w - m);
    float s = ((e[0] + e[1]) + (e[2] + e[3])) + ((e[4] + e[5]) + (e[6] + e[7]));
    #pragma unroll
    for (int o = 32; o > 0; o >>= 1) s += __shfl_xor(s, o);
    __shared__ float reds[4];
    if (lane == 0) reds[w] = s;
    __syncthreads();
    s = (reds[0] + reds[1]) + (reds[2] + reds[3]);
    const float inv = 1.0f / s;

    float4 o0, o1;
    o0.x = e[0] * inv; o0.y = e[1] * inv; o0.z = e[2] * inv; o0.w = e[3] * inv;
    o1.x = e[4] * inv; o1.y = e[5] * inv; o1.z = e[6] * inv; o1.w = e[7] * inv;
    *(float4*)(rp + tid * 8)     = o0;
    *(float4*)(rp + tid * 8 + 4) = o1;

    u16x8 pb;
    pb[0] = f2bf(o0.x); pb[1] = f2bf(o0.y); pb[2] = f2bf(o0.z); pb[3] = f2bf(o0.w);
    pb[4] = f2bf(o1.x); pb[5] = f2bf(o1.y); pb[6] = f2bf(o1.z); pb[7] = f2bf(o1.w);
    *(u16x8*)(P + (long)row * 2048 + tid * 8) = pb;
}

// ------------------------------------------------------------------ launch --
extern "C" void kernel_launch(void* const* d_in, const int* in_sizes, int n_in,
                              void* d_out, int out_size, void* d_ws, size_t ws_size,
                              hipStream_t stream) {
    const float* X  = (const float*)d_in[0];
    const float* Wq = (const float*)d_in[1];
    const float* Wk = (const float*)d_in[2];
    const float* Wv = (const float*)d_in[3];
    const float* W1 = (const float*)d_in[4];
    const float* b1 = (const float*)d_in[5];
    const float* W2 = (const float*)d_in[6];
    const float* b2 = (const float*)d_in[7];

    float* out  = (float*)d_out;                    // [4,2048,1024]
    float* attn = out + (size_t)8388608;            // [4,2048,2048]

    char* ws = (char*)d_ws;
    u16* Xb  = (u16*)(ws);                               // 16 MiB
    u16* Qb  = (u16*)(ws + (size_t)16 * 1024 * 1024);    // 16 MiB
    u16* Kb  = (u16*)(ws + (size_t)32 * 1024 * 1024);    // 16 MiB
    u16* VT  = (u16*)(ws + (size_t)48 * 1024 * 1024);    // 16 MiB  V^T [b][d][s]
    u16* H1b = (u16*)(ws + (size_t)64 * 1024 * 1024);    // 16 MiB
    u16* WTs = (u16*)(ws + (size_t)80 * 1024 * 1024);    // 10 MiB (5 x 2 MiB)
    u16* W1T = WTs + (size_t)3 * 1048576;
    u16* W2T = WTs + (size_t)4 * 1048576;
    u16* Pb  = Xb;   // 32 MiB alias over Xb+Qb (both dead by softmax time)
    u16* Hb  = Kb;   // alias over Kb (dead after scores GEMM)

    cvt_x<<<4096, 256, 0, stream>>>(X, Xb);
    cvt_wT<<<dim3(32, 32, 5), dim3(32, 8), 0, stream>>>(Wq, Wk, Wv, W1, W2, WTs);

    // fused Q,K,V: z selects weight (WTs + z*1M via sB) and output
    gemm_bt<EPI_QKV><<<dim3(64, 8, 3), 256, 0, stream>>>(
        Xb, WTs, Qb, Kb, VT, nullptr, nullptr, 8192, 1024, 1024,
        0, 1048576, 0, 0, 1.0f);

    // scores = Q @ K^T / 32  -> fp32 raw into d_out attn region
    gemm_bt<EPI_SCALE_F32><<<dim3(16, 16, 4), 256, 0, stream>>>(
        Qb, Kb, attn, nullptr, nullptr, nullptr, nullptr, 2048, 2048, 1024,
        2048L * 1024, 2048L * 1024, 2048L * 2048, 0, 0.03125f);

    softmax_rows<<<8192, 256, 0, stream>>>(attn, Pb);

    // attn_out = P @ V, + X residual -> Hb (bf16)
    gemm_bt<EPI_ADDX_BF16><<<dim3(16, 8, 4), 256, 0, stream>>>(
        Pb, VT, Hb, nullptr, nullptr, nullptr, X, 2048, 1024, 2048,
        2048L * 2048, 1024L * 2048, 2048L * 1024, 2048L * 1024, 1.0f);

    // h1 = relu(Hb @ W1 + b1)
    gemm_bt<EPI_BIAS_RELU_BF16><<<dim3(64, 8, 1), 256, 0, stream>>>(
        Hb, W1T, H1b, nullptr, nullptr, b1, nullptr, 8192, 1024, 1024,
        0, 0, 0, 0, 1.0f);

    // out = h1 @ W2 + b2 + X
    gemm_bt<EPI_BIAS_ADDX_F32><<<dim3(64, 8, 1), 256, 0, stream>>>(
        H1b, W2T, out, nullptr, nullptr, b2, X, 8192, 1024, 1024,
        0, 0, 0, 0, 1.0f);
}